// Round 1
// baseline (280.880 us; speedup 1.0000x reference)
//
#include <hip/hip_runtime.h>
#include <hip/hip_bf16.h>

// Problem: B=8, S=4096, D=768
//   y = tanh(x @ W); scores = y . v; w = softmax_S(scores); out = sum_s w * x
constexpr int Bb = 8;
constexpr int Ss = 4096;
constexpr int Dd = 768;
constexpr int Mm = Bb * Ss;      // 32768 rows

// GEMM tile config (scores kernel)
constexpr int BM = 128;
constexpr int BN = 256;
constexpr int BK = 32;
constexpr int LDA = BK + 8;      // padded LDS stride (40 bf16 = 80B) to spread banks
constexpr int NBLK = Dd / BN;    // 3 n-blocks, partial scores combined via atomics
constexpr int KSTEPS = Dd / BK;  // 24

typedef __bf16 bf16x8 __attribute__((ext_vector_type(8)));
typedef float f32x4 __attribute__((ext_vector_type(4)));

// ---------------- Kernel 0: W[k][n] fp32 -> Wt[n][k] bf16 (LDS-tiled transpose)
__global__ __launch_bounds__(256) void convW(const float* __restrict__ W,
                                             __bf16* __restrict__ Wt) {
    __shared__ float tile[32][33];
    const int tx = threadIdx.x & 31;
    const int ty = threadIdx.x >> 5;        // 0..7
    const int kb = blockIdx.x * 32;
    const int nb = blockIdx.y * 32;
#pragma unroll
    for (int i = 0; i < 32; i += 8)
        tile[ty + i][tx] = W[(size_t)(kb + ty + i) * Dd + nb + tx];
    __syncthreads();
#pragma unroll
    for (int i = 0; i < 32; i += 8)
        Wt[(size_t)(nb + ty + i) * Dd + kb + tx] = (__bf16)tile[tx][ty + i];
}

// ---------------- Kernel 1: fused scores = v . tanh(x @ W) via bf16 MFMA
// grid = (NBLK, Mm/BM), block = 256 (4 waves; wave-tile 64x128 = 4x8 MFMA 16x16 tiles)
__global__ __launch_bounds__(256, 2) void scores_gemm(
    const float* __restrict__ x, const __bf16* __restrict__ Wt,
    const float* __restrict__ v, float* __restrict__ scores) {
    __shared__ __bf16 As[BM * LDA];   // 10240 B
    __shared__ __bf16 Ws[BN * LDA];   // 20480 B

    const int t = threadIdx.x;
    const int nb = blockIdx.x;        // 0..2
    const int mb = blockIdx.y;        // 0..255

    const int lane = t & 63;
    const int wave = t >> 6;          // 0..3
    const int wm = wave >> 1;         // m half (0/1)
    const int wn = wave & 1;          // n half (0/1)
    const int quad = lane >> 4;
    const int lid = lane & 15;

    // staging assignments
    const int arow = t >> 1;                 // 0..127
    const int akh = (t & 1) * 16;            // 0 / 16
    const float* agp = x + (size_t)(mb * BM + arow) * Dd + akh;
    const __bf16* wgp = Wt + (size_t)(nb * BN + t) * Dd;

    f32x4 acc[4][8];
#pragma unroll
    for (int i = 0; i < 4; ++i)
#pragma unroll
        for (int j = 0; j < 8; ++j) acc[i][j] = (f32x4){0.f, 0.f, 0.f, 0.f};

    // prefetch k-block 0 into registers
    float4 a0 = *(const float4*)(agp + 0);
    float4 a1 = *(const float4*)(agp + 4);
    float4 a2 = *(const float4*)(agp + 8);
    float4 a3 = *(const float4*)(agp + 12);
    uint4 w0 = *(const uint4*)(wgp + 0);
    uint4 w1 = *(const uint4*)(wgp + 8);
    uint4 w2 = *(const uint4*)(wgp + 16);
    uint4 w3 = *(const uint4*)(wgp + 24);

    for (int kb = 0; kb < KSTEPS; ++kb) {
        // ---- write staged regs to LDS (A: fp32 -> bf16 convert)
        bf16x8 pa0, pa1;
        pa0[0] = (__bf16)a0.x; pa0[1] = (__bf16)a0.y; pa0[2] = (__bf16)a0.z; pa0[3] = (__bf16)a0.w;
        pa0[4] = (__bf16)a1.x; pa0[5] = (__bf16)a1.y; pa0[6] = (__bf16)a1.z; pa0[7] = (__bf16)a1.w;
        pa1[0] = (__bf16)a2.x; pa1[1] = (__bf16)a2.y; pa1[2] = (__bf16)a2.z; pa1[3] = (__bf16)a2.w;
        pa1[4] = (__bf16)a3.x; pa1[5] = (__bf16)a3.y; pa1[6] = (__bf16)a3.z; pa1[7] = (__bf16)a3.w;
        *(bf16x8*)(&As[arow * LDA + akh]) = pa0;
        *(bf16x8*)(&As[arow * LDA + akh + 8]) = pa1;
        *(uint4*)(&Ws[t * LDA + 0]) = w0;
        *(uint4*)(&Ws[t * LDA + 8]) = w1;
        *(uint4*)(&Ws[t * LDA + 16]) = w2;
        *(uint4*)(&Ws[t * LDA + 24]) = w3;
        __syncthreads();

        // ---- prefetch next k-block (overlaps MFMA below)
        if (kb + 1 < KSTEPS) {
            const float* ag = agp + (kb + 1) * BK;
            a0 = *(const float4*)(ag + 0);
            a1 = *(const float4*)(ag + 4);
            a2 = *(const float4*)(ag + 8);
            a3 = *(const float4*)(ag + 12);
            const __bf16* wg = wgp + (kb + 1) * BK;
            w0 = *(const uint4*)(wg + 0);
            w1 = *(const uint4*)(wg + 8);
            w2 = *(const uint4*)(wg + 16);
            w3 = *(const uint4*)(wg + 24);
        }

        // ---- fragments + MFMA
        bf16x8 af[4];
#pragma unroll
        for (int tm = 0; tm < 4; ++tm) {
            const int row = wm * 64 + tm * 16 + lid;
            af[tm] = *(const bf16x8*)(&As[row * LDA + quad * 8]);
        }
#pragma unroll
        for (int tn = 0; tn < 8; ++tn) {
            const int col = wn * 128 + tn * 16 + lid;
            bf16x8 bfr = *(const bf16x8*)(&Ws[col * LDA + quad * 8]);
#pragma unroll
            for (int tm = 0; tm < 4; ++tm)
                acc[tm][tn] = __builtin_amdgcn_mfma_f32_16x16x32_bf16(af[tm], bfr, acc[tm][tn], 0, 0, 0);
        }
        __syncthreads();
    }

    // ---- epilogue: score_partial[m] = sum_n v[n] * tanh(y[m][n]); reduce + atomicAdd
    float vv[8];
#pragma unroll
    for (int tn = 0; tn < 8; ++tn)
        vv[tn] = v[nb * BN + wn * 128 + tn * 16 + lid];

#pragma unroll
    for (int tm = 0; tm < 4; ++tm) {
#pragma unroll
        for (int r = 0; r < 4; ++r) {
            float s = 0.f;
#pragma unroll
            for (int tn = 0; tn < 8; ++tn) s += vv[tn] * tanhf(acc[tm][tn][r]);
            // C/D layout: col = lane&15 (n), row = quad*4 + r. Sum over the 16 cols of a quad.
            s += __shfl_xor(s, 1);
            s += __shfl_xor(s, 2);
            s += __shfl_xor(s, 4);
            s += __shfl_xor(s, 8);
            if (lid == 0) {
                const int m = mb * BM + wm * 64 + tm * 16 + quad * 4 + r;
                atomicAdd(&scores[m], s);
            }
        }
    }
}

// ---------------- Kernel 2: softmax over S per batch row
__global__ __launch_bounds__(256) void softmax_k(const float* __restrict__ scores,
                                                 float* __restrict__ weights) {
    const int b = blockIdx.x;
    const int t = threadIdx.x;
    const float* s = scores + (size_t)b * Ss;
    float* w = weights + (size_t)b * Ss;
    __shared__ float red[256];

    float mx = -1e30f;
    for (int i = t; i < Ss; i += 256) mx = fmaxf(mx, s[i]);
    red[t] = mx;
    __syncthreads();
    for (int o = 128; o > 0; o >>= 1) {
        if (t < o) red[t] = fmaxf(red[t], red[t + o]);
        __syncthreads();
    }
    mx = red[0];
    __syncthreads();

    float sum = 0.f;
    for (int i = t; i < Ss; i += 256) {
        const float e = __expf(s[i] - mx);
        w[i] = e;
        sum += e;
    }
    red[t] = sum;
    __syncthreads();
    for (int o = 128; o > 0; o >>= 1) {
        if (t < o) red[t] += red[t + o];
        __syncthreads();
    }
    const float inv = 1.f / red[0];
    for (int i = t; i < Ss; i += 256) w[i] *= inv;
}

// ---------------- Kernel 3: out[b][d] = sum_s w[b][s] * x[b][s][d]
// grid = (64 s-chunks, B), block = 192 (768/4 float4 lanes)
__global__ __launch_bounds__(192) void pool_k(const float* __restrict__ x,
                                              const float* __restrict__ weights,
                                              float* __restrict__ out) {
    const int b = blockIdx.y;
    const int sc = blockIdx.x;      // 64 chunks x 64 rows
    const int t = threadIdx.x;      // 0..191
    const int d4 = t * 4;
    float4 acc = make_float4(0.f, 0.f, 0.f, 0.f);
    const int s0 = sc * 64;
#pragma unroll 4
    for (int i = 0; i < 64; ++i) {
        const int s = s0 + i;
        const float w = weights[(size_t)b * Ss + s];
        const float4 xv = *(const float4*)(x + ((size_t)b * Ss + s) * Dd + d4);
        acc.x += w * xv.x;
        acc.y += w * xv.y;
        acc.z += w * xv.z;
        acc.w += w * xv.w;
    }
    float* o = out + (size_t)b * Dd + d4;
    atomicAdd(o + 0, acc.x);
    atomicAdd(o + 1, acc.y);
    atomicAdd(o + 2, acc.z);
    atomicAdd(o + 3, acc.w);
}

extern "C" void kernel_launch(void* const* d_in, const int* in_sizes, int n_in,
                              void* d_out, int out_size, void* d_ws, size_t ws_size,
                              hipStream_t stream) {
    (void)in_sizes; (void)n_in; (void)ws_size;
    const float* x = (const float*)d_in[0];
    const float* v = (const float*)d_in[1];
    const float* W = (const float*)d_in[2];
    float* out = (float*)d_out;

    // workspace layout
    char* ws = (char*)d_ws;
    __bf16* Wt = (__bf16*)ws;                                // 768*768*2 = 1179648 B
    float* scores = (float*)(ws + 1179648);                  // 32768*4   = 131072 B
    float* weights = (float*)(ws + 1179648 + 131072);        // 32768*4   = 131072 B

    hipMemsetAsync(scores, 0, Mm * sizeof(float), stream);
    hipMemsetAsync(d_out, 0, (size_t)out_size * sizeof(float), stream);

    convW<<<dim3(Dd / 32, Dd / 32), 256, 0, stream>>>(W, Wt);
    scores_gemm<<<dim3(NBLK, Mm / BM), 256, 0, stream>>>(x, Wt, v, scores);
    softmax_k<<<dim3(Bb), 256, 0, stream>>>(scores, weights);
    pool_k<<<dim3(64, Bb), 192, 0, stream>>>(x, weights, out);
}

// Round 2
// 250.762 us; speedup vs baseline: 1.1201x; 1.1201x over previous
//
#include <hip/hip_runtime.h>
#include <hip/hip_bf16.h>

// Problem: B=8, S=4096, D=768
//   y = tanh(x @ W); scores = y . v; w = softmax_S(scores); out = sum_s w * x
constexpr int Bb = 8;
constexpr int Ss = 4096;
constexpr int Dd = 768;
constexpr int Mm = Bb * Ss;      // 32768 rows

constexpr int BM = 64;           // rows per block (A resident in LDS)
constexpr int LDA = Dd + 8;      // 776 bf16 row stride: lane bank = 4*(lid+quad)%32 -> uniform, conflict-free b128

typedef __bf16 bf16x8 __attribute__((ext_vector_type(8)));
typedef __bf16 bf16x4 __attribute__((ext_vector_type(4)));
typedef float f32x4 __attribute__((ext_vector_type(4)));

__device__ __forceinline__ float fast_tanh(float x) {
    // tanh(x) = 1 - 2/(exp(2x)+1); v_exp_f32-based, ~1e-6 rel err (bf16 matmul err dominates)
    return 1.f - 2.f / (__expf(2.f * x) + 1.f);
}

// ---------------- Kernel 0: W[k][n] fp32 -> Wt[n][k] bf16 (LDS-tiled transpose)
__global__ __launch_bounds__(256) void convW(const float* __restrict__ W,
                                             __bf16* __restrict__ Wt) {
    __shared__ float tile[32][33];
    const int tx = threadIdx.x & 31;
    const int ty = threadIdx.x >> 5;        // 0..7
    const int kb = blockIdx.x * 32;
    const int nb = blockIdx.y * 32;
#pragma unroll
    for (int i = 0; i < 32; i += 8)
        tile[ty + i][tx] = W[(size_t)(kb + ty + i) * Dd + nb + tx];
    __syncthreads();
#pragma unroll
    for (int i = 0; i < 32; i += 8)
        Wt[(size_t)(nb + ty + i) * Dd + kb + tx] = (__bf16)tile[tx][ty + i];
}

// ---------------- Kernel 1: scores[m] = sum_n v[n]*tanh( (x@W)[m][n] )
// grid = Mm/BM = 512 blocks, 512 threads (8 waves).
// A (64 x 768) staged once in LDS; B fragments straight from L2-resident Wt.
// NO barriers in the K/N loops. Each wave owns 96 disjoint columns.
__global__ __launch_bounds__(512, 2) void scores_gemm(
    const float* __restrict__ x, const __bf16* __restrict__ Wt,
    const float* __restrict__ v, float* __restrict__ scores) {
    __shared__ __bf16 As[BM * LDA];      // 99,328 B
    __shared__ float sc_sh[8][BM];       // 2 KB cross-wave score reduce

    const int t = threadIdx.x;
    const int mb = blockIdx.x;           // 0..511
    const int lane = t & 63;
    const int w = t >> 6;                // wave 0..7
    const int quad = lane >> 4;          // k-group
    const int lid = lane & 15;           // row (A) / col (B,C)

    // ---- Phase 1: stage A rows [mb*64, mb*64+64), fp32 -> bf16, coalesced float4
    {
        const float* xb = x + (size_t)mb * BM * Dd;
#pragma unroll
        for (int i = 0; i < 24; ++i) {
            const int f = i * 512 + t;           // float4 index, 0..12287
            const int row = f / 192;             // 192 float4 per row
            const int c4 = f - row * 192;
            const float4 a = *(const float4*)(xb + (size_t)row * Dd + c4 * 4);
            bf16x4 p;
            p[0] = (__bf16)a.x; p[1] = (__bf16)a.y; p[2] = (__bf16)a.z; p[3] = (__bf16)a.w;
            *(bf16x4*)(&As[row * LDA + c4 * 4]) = p;
        }
    }
    __syncthreads();

    float racc[4][4];                    // per-lane running scores [m-tile][r]
#pragma unroll
    for (int tm = 0; tm < 4; ++tm)
#pragma unroll
        for (int r = 0; r < 4; ++r) racc[tm][r] = 0.f;

#pragma unroll
    for (int iter = 0; iter < 2; ++iter) {
        const int colbase = iter * 384 + w * 48;     // 8 waves x 2 iters x 48 cols = 768
        const __bf16* wp0 = Wt + (size_t)(colbase + 0  + lid) * Dd + quad * 8;
        const __bf16* wp1 = Wt + (size_t)(colbase + 16 + lid) * Dd + quad * 8;
        const __bf16* wp2 = Wt + (size_t)(colbase + 32 + lid) * Dd + quad * 8;

        f32x4 acc[4][3];
#pragma unroll
        for (int tm = 0; tm < 4; ++tm)
#pragma unroll
            for (int nt = 0; nt < 3; ++nt) acc[tm][nt] = (f32x4){0.f, 0.f, 0.f, 0.f};

        // register prefetch of B fragments (L2-hot)
        bf16x8 b0 = *(const bf16x8*)(wp0);
        bf16x8 b1 = *(const bf16x8*)(wp1);
        bf16x8 b2 = *(const bf16x8*)(wp2);

#pragma unroll
        for (int kb = 0; kb < 24; ++kb) {
            bf16x8 n0, n1, n2;
            if (kb < 23) {                            // compile-time per unrolled copy
                n0 = *(const bf16x8*)(wp0 + (kb + 1) * 32);
                n1 = *(const bf16x8*)(wp1 + (kb + 1) * 32);
                n2 = *(const bf16x8*)(wp2 + (kb + 1) * 32);
            }
            bf16x8 af[4];
#pragma unroll
            for (int tm = 0; tm < 4; ++tm)
                af[tm] = *(const bf16x8*)(&As[(tm * 16 + lid) * LDA + kb * 32 + quad * 8]);
#pragma unroll
            for (int tm = 0; tm < 4; ++tm) {
                acc[tm][0] = __builtin_amdgcn_mfma_f32_16x16x32_bf16(af[tm], b0, acc[tm][0], 0, 0, 0);
                acc[tm][1] = __builtin_amdgcn_mfma_f32_16x16x32_bf16(af[tm], b1, acc[tm][1], 0, 0, 0);
                acc[tm][2] = __builtin_amdgcn_mfma_f32_16x16x32_bf16(af[tm], b2, acc[tm][2], 0, 0, 0);
            }
            b0 = n0; b1 = n1; b2 = n2;
        }

        // fold this iter's 48 columns into running row scores
        const float v0 = v[colbase + 0 + lid];
        const float v1 = v[colbase + 16 + lid];
        const float v2 = v[colbase + 32 + lid];
#pragma unroll
        for (int tm = 0; tm < 4; ++tm)
#pragma unroll
            for (int r = 0; r < 4; ++r)
                racc[tm][r] += v0 * fast_tanh(acc[tm][0][r])
                             + v1 * fast_tanh(acc[tm][1][r])
                             + v2 * fast_tanh(acc[tm][2][r]);
    }

    // ---- reduce over the 16 cols held across lid lanes (C layout: col=lid, row=quad*4+r)
#pragma unroll
    for (int tm = 0; tm < 4; ++tm)
#pragma unroll
        for (int r = 0; r < 4; ++r) {
            float s = racc[tm][r];
            s += __shfl_xor(s, 1);
            s += __shfl_xor(s, 2);
            s += __shfl_xor(s, 4);
            s += __shfl_xor(s, 8);
            if (lid == 0) sc_sh[w][tm * 16 + quad * 4 + r] = s;
        }
    __syncthreads();
    if (t < BM) {
        float s = 0.f;
#pragma unroll
        for (int ww = 0; ww < 8; ++ww) s += sc_sh[ww][t];
        scores[mb * BM + t] = s;
    }
}

// ---------------- Kernel 2: fused softmax + pool
// out[b][d] = sum_s softmax(scores[b])[s] * x[b][s][d]
// grid = (32 s-chunks, B), 256 threads; each block redoes the (cheap, L2-hot) softmax stats.
__global__ __launch_bounds__(256) void pool_k(const float* __restrict__ x,
                                              const float* __restrict__ scores,
                                              float* __restrict__ out) {
    const int b = blockIdx.y;
    const int sc = blockIdx.x;           // 32 chunks x 128 rows
    const int t = threadIdx.x;
    const float* srow = scores + (size_t)b * Ss;
    __shared__ float red[256];

    float mx = -1e30f;
    for (int i = t; i < Ss; i += 256) mx = fmaxf(mx, srow[i]);
    red[t] = mx;
    __syncthreads();
    for (int o = 128; o > 0; o >>= 1) {
        if (t < o) red[t] = fmaxf(red[t], red[t + o]);
        __syncthreads();
    }
    mx = red[0];
    __syncthreads();
    float sum = 0.f;
    for (int i = t; i < Ss; i += 256) sum += __expf(srow[i] - mx);
    red[t] = sum;
    __syncthreads();
    for (int o = 128; o > 0; o >>= 1) {
        if (t < o) red[t] += red[t + o];
        __syncthreads();
    }
    const float inv = 1.f / red[0];

    float a0 = 0.f, a1 = 0.f, a2 = 0.f;
    const int s0 = sc * 128;
#pragma unroll 4
    for (int i = 0; i < 128; ++i) {
        const int s = s0 + i;
        const float ww = __expf(srow[s] - mx) * inv;
        const float* xr = x + ((size_t)b * Ss + s) * Dd;
        a0 += ww * xr[t];
        a1 += ww * xr[t + 256];
        a2 += ww * xr[t + 512];
    }
    float* o = out + (size_t)b * Dd;
    atomicAdd(o + t, a0);
    atomicAdd(o + t + 256, a1);
    atomicAdd(o + t + 512, a2);
}

extern "C" void kernel_launch(void* const* d_in, const int* in_sizes, int n_in,
                              void* d_out, int out_size, void* d_ws, size_t ws_size,
                              hipStream_t stream) {
    (void)in_sizes; (void)n_in; (void)ws_size;
    const float* x = (const float*)d_in[0];
    const float* v = (const float*)d_in[1];
    const float* W = (const float*)d_in[2];

    // workspace layout
    char* ws = (char*)d_ws;
    __bf16* Wt = (__bf16*)ws;                          // 768*768*2 = 1,179,648 B
    float* scores = (float*)(ws + 1179648);            // 32768*4   =   131,072 B

    hipMemsetAsync(d_out, 0, (size_t)out_size * sizeof(float), stream);

    convW<<<dim3(Dd / 32, Dd / 32), 256, 0, stream>>>(W, Wt);
    scores_gemm<<<dim3(Mm / BM), 512, 0, stream>>>(x, Wt, v, scores);
    pool_k<<<dim3(32, Bb), 256, 0, stream>>>(x, scores, d_out ? (float*)d_out : nullptr);
}